// Round 16
// baseline (67.891 us; speedup 1.0000x reference)
//
#include <hip/hip_runtime.h>
#include <hip/hip_bf16.h>

#define SEQ  4096
#define HEADS 8
#define IND  256
#define OUTD 64
#define NSPLIT 4
#define QBLK 128
#define TILES_PER_SLICE (SEQ / 64 / NSPLIT)   // 16

typedef __attribute__((ext_vector_type(8))) short bf16x8;
typedef __attribute__((ext_vector_type(4))) float f32x4;

__device__ __forceinline__ unsigned short f2bf(float f) {
  union { __hip_bfloat16 h; unsigned short u; } c;
  c.h = __float2bfloat16(f);
  return c.u;
}
__device__ __forceinline__ float bf2f(unsigned short u) {
  union { unsigned u; float f; } c;
  c.u = ((unsigned)u) << 16;
  return c.f;
}
// raw v_exp_f32: skips OCML's denorm-range fixup (scores are in [-30, 14];
// masked -1e30 gives exact 0 in HW)
__device__ __forceinline__ float fast_exp2(float x) {
#if __has_builtin(__builtin_amdgcn_exp2f)
  return __builtin_amdgcn_exp2f(x);
#else
  float r;
  asm("v_exp_f32 %0, %1" : "=v"(r) : "v"(x));
  return r;
#endif
}
// ONE v_perm_b32: pack hi16(hi), hi16(lo) -> dword of 2 bf16 (truncation)
__device__ __forceinline__ unsigned pk2(float hi, float lo) {
  return __builtin_amdgcn_perm(__builtin_bit_cast(unsigned, hi),
                               __builtin_bit_cast(unsigned, lo), 0x07060302u);
}
// bijective column permutation for V^T tiles (key -> col') so the PV
// A-fragment k-slots line up with pb: col' bits = [k5][k3 k2][k4][k1 k0]
__device__ __forceinline__ int pcol(int k) {
  return (k >> 5) * 32 + ((k >> 2) & 3) * 8 + ((k >> 4) & 1) * 4 + (k & 3);
}

// ---------------------------------------------------------------------------
// prep: W[h][i][d] -> WT[h][d][i] bf16 (WQ scaled 1/8*log2e); lin_w -> bf16.
// ---------------------------------------------------------------------------
__global__ void prep_kernel(const float* __restrict__ WQ,
                            const float* __restrict__ WK,
                            const float* __restrict__ WV,
                            const float* __restrict__ LW,
                            unsigned short* __restrict__ WTQ,
                            unsigned short* __restrict__ WTK,
                            unsigned short* __restrict__ WTV,
                            unsigned short* __restrict__ LWB) {
  const int NW = HEADS * IND * OUTD;  // 131072
  const int NL = OUTD * HEADS * OUTD; // 32768
  int i = blockIdx.x * 256 + threadIdx.x;
  if (i < 3 * NW) {
    int which = i / NW;
    int r = i % NW;
    int h = r / (IND * OUTD);
    int rem = r % (IND * OUTD);
    int d = rem / IND;
    int ii = rem % IND;
    const float* W = (which == 0) ? WQ : ((which == 1) ? WK : WV);
    float v = W[(h * IND + ii) * OUTD + d];
    if (which == 0) v *= 0.125f * 1.44269504088896f;  // 1/sqrt(64) * log2(e)
    unsigned short* DST = (which == 0) ? WTQ : ((which == 1) ? WTK : WTV);
    DST[h * OUTD * IND + d * IND + ii] = f2bf(v);
  } else if (i < 3 * NW + NL) {
    int k = i - 3 * NW;
    LWB[k] = f2bf(LW[k]);
  }
}

// ---------------------------------------------------------------------------
// Projections, merged: one block computes Q (row-major), K and V^T as
// SWIZZLED 8KB tile images for attn's global_load_lds staging:
//   tile image element (row, colseg c, sub j): ushort idx =
//     row*64 + ((c ^ (row&7))<<3) + j      (128B rows, XOR'd 16B segments)
// K: row = key_in_tile, col = d. V: row = d, col' = pcol(key_in_tile).
// X converted f32->bf16 inline. grid (64 token blocks, 8 heads) x 256.
// ---------------------------------------------------------------------------
__global__ __launch_bounds__(256) void proj_kernel(
    const float* __restrict__ X,
    const unsigned short* __restrict__ WTQ,
    const unsigned short* __restrict__ WTK,
    const unsigned short* __restrict__ WTV,
    unsigned short* __restrict__ Qo,
    unsigned short* __restrict__ KS,
    unsigned short* __restrict__ VS) {
  const int tb = blockIdx.x;
  const int h  = blockIdx.y;

  __shared__ unsigned short Xl[64 * 72];
  __shared__ unsigned short Wl[3][64 * 72];

  const int tid = threadIdx.x;
  const int lane = tid & 63;
  const int w = tid >> 6;
  const int m16 = lane & 15;
  const int g = lane >> 4;

  const unsigned short* W0 = WTQ + h * OUTD * IND;
  const unsigned short* W1 = WTK + h * OUTD * IND;
  const unsigned short* W2 = WTV + h * OUTD * IND;

  f32x4 acc[3][4];
#pragma unroll
  for (int z = 0; z < 3; ++z)
#pragma unroll
    for (int ns = 0; ns < 4; ++ns) {
      f32x4 z4 = {0.f, 0.f, 0.f, 0.f};
      acc[z][ns] = z4;
    }

  for (int kb = 0; kb < 4; ++kb) {
    if (kb) __syncthreads();
    for (int s = tid; s < 512; s += 256) {
      int row = s >> 3, sg = s & 7;
      const float* xs = X + (size_t)(tb * 64 + row) * IND + kb * 64 + sg * 8;
      float4 x0 = *(const float4*)xs;
      float4 x1 = *(const float4*)(xs + 4);
      uint4 u;
      u.x = ((unsigned)f2bf(x0.y) << 16) | f2bf(x0.x);
      u.y = ((unsigned)f2bf(x0.w) << 16) | f2bf(x0.z);
      u.z = ((unsigned)f2bf(x1.y) << 16) | f2bf(x1.x);
      u.w = ((unsigned)f2bf(x1.w) << 16) | f2bf(x1.z);
      *(uint4*)(&Xl[row * 72 + sg * 8]) = u;
      *(uint4*)(&Wl[0][row * 72 + sg * 8]) =
          *(const uint4*)(W0 + (size_t)row * IND + kb * 64 + sg * 8);
      *(uint4*)(&Wl[1][row * 72 + sg * 8]) =
          *(const uint4*)(W1 + (size_t)row * IND + kb * 64 + sg * 8);
      *(uint4*)(&Wl[2][row * 72 + sg * 8]) =
          *(const uint4*)(W2 + (size_t)row * IND + kb * 64 + sg * 8);
    }
    __syncthreads();
    bf16x8 xa0 = *(const bf16x8*)(&Xl[(w * 16 + m16) * 72 + g * 8]);
    bf16x8 xa1 = *(const bf16x8*)(&Xl[(w * 16 + m16) * 72 + 32 + g * 8]);
#pragma unroll
    for (int z = 0; z < 2; ++z)
#pragma unroll
      for (int ns = 0; ns < 4; ++ns) {
        bf16x8 b0 = *(const bf16x8*)(&Wl[z][(ns * 16 + m16) * 72 + g * 8]);
        bf16x8 b1 = *(const bf16x8*)(&Wl[z][(ns * 16 + m16) * 72 + 32 + g * 8]);
        acc[z][ns] = __builtin_amdgcn_mfma_f32_16x16x32_bf16(xa0, b0, acc[z][ns], 0, 0, 0);
        acc[z][ns] = __builtin_amdgcn_mfma_f32_16x16x32_bf16(xa1, b1, acc[z][ns], 0, 0, 0);
      }
    bf16x8 wa0 = *(const bf16x8*)(&Wl[2][(w * 16 + m16) * 72 + g * 8]);
    bf16x8 wa1 = *(const bf16x8*)(&Wl[2][(w * 16 + m16) * 72 + 32 + g * 8]);
#pragma unroll
    for (int ns = 0; ns < 4; ++ns) {
      bf16x8 b0 = *(const bf16x8*)(&Xl[(ns * 16 + m16) * 72 + g * 8]);
      bf16x8 b1 = *(const bf16x8*)(&Xl[(ns * 16 + m16) * 72 + 32 + g * 8]);
      acc[2][ns] = __builtin_amdgcn_mfma_f32_16x16x32_bf16(wa0, b0, acc[2][ns], 0, 0, 0);
      acc[2][ns] = __builtin_amdgcn_mfma_f32_16x16x32_bf16(wa1, b1, acc[2][ns], 0, 0, 0);
    }
  }
#pragma unroll
  for (int ns = 0; ns < 4; ++ns)
#pragma unroll
    for (int r = 0; r < 4; ++r) {
      int token = tb * 64 + w * 16 + 4 * g + r;
      int d = ns * 16 + m16;
      Qo[(size_t)h * SEQ * OUTD + (size_t)token * OUTD + d] = f2bf(acc[0][ns][r]);
    }
  {
    unsigned short* O = KS + ((size_t)(h * 64 + tb)) * 4096;
#pragma unroll
    for (int ns = 0; ns < 4; ++ns)
#pragma unroll
      for (int r = 0; r < 4; ++r) {
        int rk = w * 16 + 4 * g + r;
        int d = ns * 16 + m16;
        int c = d >> 3;
        int idx = rk * 64 + ((c ^ (rk & 7)) << 3) + (d & 7);
        O[idx] = f2bf(acc[1][ns][r]);
      }
  }
  {
    unsigned short* O = VS + ((size_t)(h * 64 + tb)) * 4096;
#pragma unroll
    for (int ns = 0; ns < 4; ++ns) {
      int cp = pcol(ns * 16 + m16);
      int c = cp >> 3, j = cp & 7;
#pragma unroll
      for (int r = 0; r < 4; ++r) {
        int rv = w * 16 + 4 * g + r;
        int idx = rv * 64 + ((c ^ (rv & 7)) << 3) + j;
        O[idx] = f2bf(acc[2][ns][r]);
      }
    }
  }
}

// ---------------------------------------------------------------------------
// Flash attention, ONE-TILE PIPELINE at 4 blocks/CU, RACE-FIXED epochs:
// iter t: stageV(t) [top: its buffer's last reader pv(t-2) is behind the
// end-of-(t-1) barrier], stageK(t+2), QK(t) MFMAs, PV(t-1) MFMAs (pb from
// last iter; independent, queue behind QK), exp2(t) drains both. Counted
// vmcnt(2) steady state (K(t+2) flies; V(t)+K(t+1) landed at barrier);
// vmcnt(0) for the last two in-loop barriers. 40KB LDS (K 3-buf, V 2-buf).
// P = raw v_exp(S); l on the MFMA pipe. grid (32 qb, 8 heads, 4 sl) x 256.
// ---------------------------------------------------------------------------
__global__ __launch_bounds__(256, 4) void attn_kernel(
    const unsigned short* __restrict__ Q,
    const unsigned short* __restrict__ KS,
    const unsigned short* __restrict__ VS,
    unsigned short* __restrict__ PART,   // [NSPLIT][H][SEQ][OUTD] bf16
    float* __restrict__ L) {             // [NSPLIT][H][SEQ]
  const int qb = blockIdx.x;
  const int h  = blockIdx.y;
  const int sl = blockIdx.z;
  const int kb0 = sl * TILES_PER_SLICE;
  const unsigned short* Qh = Q + (size_t)h * SEQ * OUTD;

  __shared__ unsigned short Kl[3][4096];
  __shared__ unsigned short Vl[2][4096];

  const int tid = threadIdx.x;
  const int lane = tid & 63;
  const int w = tid >> 6;
  const int m16 = lane & 15;
  const int g = lane >> 4;
  const int e = m16 & 7;
  const int c0s = ((g ^ e) << 3);          // ushort offset of d-seg g
  const int c1s = (((g + 4) ^ e) << 3);    // ushort offset of d-seg g+4

  const int qrowA = qb * QBLK + w * 16 + m16;
  const int qrowB = qrowA + 64;
  bf16x8 qfA0 = *(const bf16x8*)(Qh + (size_t)qrowA * OUTD + g * 8);
  bf16x8 qfA1 = *(const bf16x8*)(Qh + (size_t)qrowA * OUTD + 32 + g * 8);
  bf16x8 qfB0 = *(const bf16x8*)(Qh + (size_t)qrowB * OUTD + g * 8);
  bf16x8 qfB1 = *(const bf16x8*)(Qh + (size_t)qrowB * OUTD + 32 + g * 8);

  f32x4 accA[4], accB[4], acc5A, acc5B;
#pragma unroll
  for (int s4 = 0; s4 < 4; ++s4) {
    f32x4 z4 = {0.f, 0.f, 0.f, 0.f};
    accA[s4] = z4; accB[s4] = z4;
  }
  { f32x4 z4 = {0.f, 0.f, 0.f, 0.f}; acc5A = z4; acc5B = z4; }
  const f32x4 zero4 = {0.f, 0.f, 0.f, 0.f};
  bf16x8 ones;
#pragma unroll
  for (int j = 0; j < 8; ++j) ones[j] = (short)0x3F80;  // bf16 1.0

  // per-lane global source pointers into the swizzled tile streams
  const unsigned short* kg = KS + ((size_t)(h * 64 + kb0)) * 4096 + w * 512 + lane * 8;
  const unsigned short* vg = VS + ((size_t)(h * 64 + kb0)) * 4096 + w * 512 + lane * 8;

  auto stageK = [&](int buf) {
    __builtin_amdgcn_global_load_lds(kg, &Kl[buf][w * 512], 16, 0, 0);
    __builtin_amdgcn_global_load_lds(kg + 2048, &Kl[buf][2048 + w * 512], 16, 0, 0);
    kg += 4096;
  };
  auto stageV = [&](int buf) {
    __builtin_amdgcn_global_load_lds(vg, &Vl[buf][w * 512], 16, 0, 0);
    __builtin_amdgcn_global_load_lds(vg + 2048, &Vl[buf][2048 + w * 512], 16, 0, 0);
    vg += 4096;
  };

  // pipeline state: packed P of the previous tile; QK scratch
  bf16x8 pbA0, pbA1, pbB0, pbB1;
  f32x4 stA[4], stB[4];

  auto qk_mfma = [&](int kcur) {
    __builtin_amdgcn_s_setprio(1);
#pragma unroll
    for (int t = 0; t < 4; ++t) {
      const unsigned short* krow = &Kl[kcur][(t * 16 + m16) * 64];
      bf16x8 ka0 = *(const bf16x8*)(krow + c0s);
      bf16x8 ka1 = *(const bf16x8*)(krow + c1s);
      stA[t] = __builtin_amdgcn_mfma_f32_16x16x32_bf16(ka0, qfA0, zero4, 0, 0, 0);
      stA[t] = __builtin_amdgcn_mfma_f32_16x16x32_bf16(ka1, qfA1, stA[t], 0, 0, 0);
      stB[t] = __builtin_amdgcn_mfma_f32_16x16x32_bf16(ka0, qfB0, zero4, 0, 0, 0);
      stB[t] = __builtin_amdgcn_mfma_f32_16x16x32_bf16(ka1, qfB1, stB[t], 0, 0, 0);
    }
    __builtin_amdgcn_s_setprio(0);
  };

  auto pv_step = [&](int vbuf) {
    __builtin_amdgcn_s_setprio(1);
#pragma unroll
    for (int s4 = 0; s4 < 4; ++s4) {
      const unsigned short* vrow = &Vl[vbuf][(s4 * 16 + m16) * 64];
      bf16x8 va0 = *(const bf16x8*)(vrow + c0s);
      bf16x8 va1 = *(const bf16x8*)(vrow + c1s);
      accA[s4] = __builtin_amdgcn_mfma_f32_16x16x32_bf16(va0, pbA0, accA[s4], 0, 0, 0);
      accA[s4] = __builtin_amdgcn_mfma_f32_16x16x32_bf16(va1, pbA1, accA[s4], 0, 0, 0);
      accB[s4] = __builtin_amdgcn_mfma_f32_16x16x32_bf16(va0, pbB0, accB[s4], 0, 0, 0);
      accB[s4] = __builtin_amdgcn_mfma_f32_16x16x32_bf16(va1, pbB1, accB[s4], 0, 0, 0);
    }
    acc5A = __builtin_amdgcn_mfma_f32_16x16x32_bf16(ones, pbA0, acc5A, 0, 0, 0);
    acc5A = __builtin_amdgcn_mfma_f32_16x16x32_bf16(ones, pbA1, acc5A, 0, 0, 0);
    acc5B = __builtin_amdgcn_mfma_f32_16x16x32_bf16(ones, pbB0, acc5B, 0, 0, 0);
    acc5B = __builtin_amdgcn_mfma_f32_16x16x32_bf16(ones, pbB1, acc5B, 0, 0, 0);
    __builtin_amdgcn_s_setprio(0);
  };

  auto mask_pack = [&](int kbg) {
    if (kbg == 2 * qb) {
#pragma unroll
      for (int t = 0; t < 4; ++t)
#pragma unroll
        for (int r = 0; r < 4; ++r)
          if (t == w && (4 * g + r) == m16) stA[t][r] = -1e30f;
    }
    if (kbg == 2 * qb + 1) {
#pragma unroll
      for (int t = 0; t < 4; ++t)
#pragma unroll
        for (int r = 0; r < 4; ++r)
          if (t == w && (4 * g + r) == m16) stB[t][r] = -1e30f;
    }
    float eA[16], eB[16];
#pragma unroll
    for (int t = 0; t < 4; ++t)
#pragma unroll
      for (int r = 0; r < 4; ++r) {
        eA[t * 4 + r] = fast_exp2(stA[t][r]);
        eB[t * 4 + r] = fast_exp2(stB[t][r]);
      }
    uint4 uA0, uA1, uB0, uB1;
    uA0.x = pk2(eA[1], eA[0]);   uA0.y = pk2(eA[3], eA[2]);
    uA0.z = pk2(eA[5], eA[4]);   uA0.w = pk2(eA[7], eA[6]);
    uA1.x = pk2(eA[9], eA[8]);   uA1.y = pk2(eA[11], eA[10]);
    uA1.z = pk2(eA[13], eA[12]); uA1.w = pk2(eA[15], eA[14]);
    uB0.x = pk2(eB[1], eB[0]);   uB0.y = pk2(eB[3], eB[2]);
    uB0.z = pk2(eB[5], eB[4]);   uB0.w = pk2(eB[7], eB[6]);
    uB1.x = pk2(eB[9], eB[8]);   uB1.y = pk2(eB[11], eB[10]);
    uB1.z = pk2(eB[13], eB[12]); uB1.w = pk2(eB[15], eB[14]);
    pbA0 = __builtin_bit_cast(bf16x8, uA0);
    pbA1 = __builtin_bit_cast(bf16x8, uA1);
    pbB0 = __builtin_bit_cast(bf16x8, uB0);
    pbB1 = __builtin_bit_cast(bf16x8, uB1);
  };

  // prologue: K(0), K(1); wait K(0) landed -> K(1)x2 stays in flight
  stageK(0);
  stageK(1);
  asm volatile("s_waitcnt vmcnt(2)" ::: "memory");
  __builtin_amdgcn_s_barrier();
  asm volatile("" ::: "memory");

#pragma unroll
  for (int it = 0; it < TILES_PER_SLICE; ++it) {
    // stageV(t): Vl[t&1]'s last reader was pv(t-2) at iter t-1, behind the
    // end-of-(t-1) barrier -> safe. V(t) consumed by pv(t) at iter t+1.
    if (it < TILES_PER_SLICE) stageV(it & 1);
    if (it + 2 < TILES_PER_SLICE) stageK((it + 2) % 3);

    qk_mfma(it % 3);                    // QK(t): MFMAs queued, wave continues
    if (it > 0) pv_step((it - 1) & 1);  // PV(t-1): independent MFMAs queued

    mask_pack(kb0 + it);  // exp2(t) waits on QK(t); queued MFMAs drain under it

    if (it < TILES_PER_SLICE - 1) {
      if (it < TILES_PER_SLICE - 2) {
        // queue: K(t+1)x2, V(t)x2, K(t+2)x2 -> vmcnt(2) lands K(t+1)+V(t)
        asm volatile("s_waitcnt vmcnt(2)" ::: "memory");
      } else {
        // it == N-2: queue = K(N-1)x2, V(N-2)x2; vmcnt(2) would leave V flying
        asm volatile("s_waitcnt vmcnt(0)" ::: "memory");
      }
      __builtin_amdgcn_s_barrier();
      asm volatile("" ::: "memory");
    }
  }
  // drain: V(N-1) must be landed block-wide before PV(N-1)
  asm volatile("s_waitcnt vmcnt(0)" ::: "memory");
  __builtin_amdgcn_s_barrier();
  asm volatile("" ::: "memory");
  pv_step((TILES_PER_SLICE - 1) & 1);

  // epilogue: unnormalized partial O^T (bf16, perm-trunc) + l per q-group
  const size_t baseA = (((size_t)sl * HEADS + h) * SEQ + qrowA) * OUTD;
  const size_t baseB = (((size_t)sl * HEADS + h) * SEQ + qrowB) * OUTD;
#pragma unroll
  for (int s4 = 0; s4 < 4; ++s4) {
    uint2 pkA, pkB;
    pkA.x = pk2(accA[s4][1], accA[s4][0]);
    pkA.y = pk2(accA[s4][3], accA[s4][2]);
    pkB.x = pk2(accB[s4][1], accB[s4][0]);
    pkB.y = pk2(accB[s4][3], accB[s4][2]);
    *(uint2*)(&PART[baseA + s4 * 16 + 4 * g]) = pkA;
    *(uint2*)(&PART[baseB + s4 * 16 + 4 * g]) = pkB;
  }
  if (g == 0) {
    L[((size_t)sl * HEADS + h) * SEQ + qrowA] = acc5A[0];
    L[((size_t)sl * HEADS + h) * SEQ + qrowB] = acc5B[0];
  }
}

// ---------------------------------------------------------------------------
// Final linear as MFMA GEMM, 4 waves (2 heads each) + 3-way LDS reduce
// (stride 20 floats: conflict-free). A-frags built in registers from the
// 4-way split-K combine. grid 256 x 256; 16 tokens per block.
// ---------------------------------------------------------------------------
__global__ __launch_bounds__(256) void final_kernel(
    const unsigned short* __restrict__ PART, const float* __restrict__ L,
    const unsigned short* __restrict__ LWB, const float* __restrict__ LB,
    float* __restrict__ OUT) {
  __shared__ float Rl[3][64 * 20];
  const int q0 = blockIdx.x * 16;
  const int tid = threadIdx.x;
  const int wv = tid >> 6, lane = tid & 63;
  const int m16 = lane & 15, g = lane >> 4;

  f32x4 acc[4];
#pragma unroll
  for (int ns = 0; ns < 4; ++ns) { f32x4 z4 = {0.f, 0.f, 0.f, 0.f}; acc[ns] = z4; }

#pragma unroll
  for (int kbi = 0; kbi < 2; ++kbi) {
    const int kb = wv * 2 + kbi;
    float lsum = 0.f;
#pragma unroll
    for (int s2 = 0; s2 < NSPLIT; ++s2)
      lsum += L[((size_t)s2 * HEADS + kb) * SEQ + q0 + m16];
    float inv = 1.f / lsum;
    float va[8], vb[8];
#pragma unroll
    for (int j = 0; j < 8; ++j) { va[j] = 0.f; vb[j] = 0.f; }
#pragma unroll
    for (int s2 = 0; s2 < NSPLIT; ++s2) {
      const unsigned short* p =
          PART + (((size_t)s2 * HEADS + kb) * SEQ + q0 + m16) * OUTD;
      bf16x8 t0 = *(const bf16x8*)(p + g * 8);
      bf16x8 t1 = *(const bf16x8*)(p + 32 + g * 8);
#pragma unroll
      for (int j = 0; j < 8; ++j) {
        va[j] += bf2f((unsigned short)t0[j]);
        vb[j] += bf2f((unsigned short)t1[j]);
      }
    }
    uint4 u0, u1;
    u0.x = pk2(va[1] * inv, va[0] * inv); u0.y = pk2(va[3] * inv, va[2] * inv);
    u0.z = pk2(va[5] * inv, va[4] * inv); u0.w = pk2(va[7] * inv, va[6] * inv);
    u1.x = pk2(vb[1] * inv, vb[0] * inv); u1.y = pk2(vb[3] * inv, vb[2] * inv);
    u1.z = pk2(vb[5] * inv, vb[4] * inv); u1.w = pk2(vb[7] * inv, vb[6] * inv);
    bf16x8 a0 = __builtin_bit_cast(bf16x8, u0);
    bf16x8 a1 = __builtin_bit_cast(bf16x8, u1);
#pragma unroll
    for (int ns = 0; ns < 4; ++ns) {
      const unsigned short* lw = LWB + (size_t)(ns * 16 + m16) * 512 + kb * 64;
      bf16x8 b0 = *(const bf16x8*)(lw + g * 8);
      bf16x8 b1 = *(const bf16x8*)(lw + 32 + g * 8);
      acc[ns] = __builtin_amdgcn_mfma_f32_16x16x32_bf16(a0, b0, acc[ns], 0, 0, 0);
      acc[ns] = __builtin_amdgcn_mfma_f32_16x16x32_bf16(a1, b1, acc[ns], 0, 0, 0);
    }
  }

  if (wv != 0) {
#pragma unroll
    for (int ns = 0; ns < 4; ++ns)
      *(f32x4*)(&Rl[wv - 1][lane * 20 + ns * 4]) = acc[ns];
  }
  __syncthreads();
  if (wv == 0) {
#pragma unroll
    for (int ns = 0; ns < 4; ++ns) {
      f32x4 o = acc[ns];
#pragma unroll
      for (int rr = 0; rr < 3; ++rr)
        o += *(const f32x4*)(&Rl[rr][lane * 20 + ns * 4]);
      float b = LB[ns * 16 + m16];
#pragma unroll
      for (int r = 0; r < 4; ++r)
        OUT[(size_t)(q0 + 4 * g + r) * OUTD + ns * 16 + m16] = o[r] + b;
    }
  }
}

// ---------------------------------------------------------------------------
extern "C" void kernel_launch(void* const* d_in, const int* in_sizes, int n_in,
                              void* d_out, int out_size, void* d_ws, size_t ws_size,
                              hipStream_t stream) {
  const float* X  = (const float*)d_in[0];
  const float* WQ = (const float*)d_in[1];
  const float* WK = (const float*)d_in[2];
  const float* WV = (const float*)d_in[3];
  const float* LW = (const float*)d_in[4];
  const float* LB = (const float*)d_in[5];

  char* ws = (char*)d_ws;
  unsigned short* Qb  = (unsigned short*)ws;
  unsigned short* KS  = Qb + (size_t)HEADS * SEQ * OUTD;
  unsigned short* VS  = KS + (size_t)HEADS * SEQ * OUTD;
  unsigned short* LWB = VS + (size_t)HEADS * SEQ * OUTD;
  char* region2 = (char*)(LWB + (size_t)OUTD * HEADS * OUTD);

  unsigned short* WTQ = (unsigned short*)region2;
  unsigned short* WTK = WTQ + (size_t)HEADS * OUTD * IND;
  unsigned short* WTV = WTK + (size_t)HEADS * OUTD * IND;

  unsigned short* PART = (unsigned short*)region2;           // aliases WT*
  float* Lml = (float*)(region2 + (size_t)NSPLIT * HEADS * SEQ * OUTD * 2);

  const int total_prep = 3 * HEADS * IND * OUTD + OUTD * HEADS * OUTD;
  prep_kernel<<<(total_prep + 255) / 256, 256, 0, stream>>>(
      WQ, WK, WV, LW, WTQ, WTK, WTV, LWB);
  proj_kernel<<<dim3(64, 8), 256, 0, stream>>>(X, WTQ, WTK, WTV, Qb, KS, VS);
  attn_kernel<<<dim3(SEQ / QBLK, 8, NSPLIT), 256, 0, stream>>>(Qb, KS, VS, PART, Lml);
  final_kernel<<<256, 256, 0, stream>>>(PART, Lml, LWB, LB, (float*)d_out);
}